// Round 7
// baseline (260.235 us; speedup 1.0000x reference)
//
#include <hip/hip_runtime.h>
#include <stdint.h>

#define NN 2048

// ---------- kernel A: precompute (c,s) table into workspace (idempotent) ----------
__global__ void cs_init_kernel(const float* __restrict__ angles, float2* __restrict__ cs) {
    const int i = blockIdx.x * blockDim.x + threadIdx.x;
    if (i < NN) {
        float s, c;
        sincosf(angles[i], &s, &c);
        cs[i] = make_float2(c, s);
    }
}

// ---------- kernel B: one BLOCK = 2 rows, single shot (no loop). ----------
// Thread t owns elements [8t, 8t+8) of both rows. Affine-carry suffix scan
// (math identical to rounds 1-6, all PASSED):
//   a_k = c_k*x[k] - s_k*a_{k+1},  y[k+1] = s_k*x[k] + c_k*a_{k+1},
//   carry into k=2047 is x[0]; element 0 consumes t0 = s*x[2047]+c*x[0];
//   y[0] = final carry (thread 0).
// Round-7 changes:
//  - __launch_bounds__(256,8): VGPR cap 64 -> 8 waves/SIMD (R6 self-capped at 4).
//  - 8192 blocks, one 2-row shot each: MLP comes from 8 resident blocks/CU.
//  - 2 rows interleaved everywhere (halves chain latency per row).
//  - barrier count 2 per block (was 2 per row): cross-wave e7 edge is computed
//    locally from the INCLUSIVE scan value (= incoming carry of thread t-1):
//    y[8t] = c_{8t-1}*aPrev + s_{8t-1}*x[8t-1],  aPrev = U_incl + M_incl*h.
__global__ __launch_bounds__(256, 8) void ring_rows2_kernel(
        const float* __restrict__ x,
        const float2* __restrict__ cs,
        float* __restrict__ y,
        int B) {
    __shared__ float tmL[4];        // wave M totals (setup)
    __shared__ float tuL[2][4];     // per-row wave U totals
    const int tid  = threadIdx.x;
    const int lane = tid & 63;
    const int wv   = tid >> 6;

    const int row0 = blockIdx.x * 2;
    if (row0 >= B) return;
    const int row1  = min(row0 + 1, B - 1);
    const bool st1  = (row0 + 1 < B);

    const float* __restrict__ xr0 = x + (size_t)row0 * NN;
    const float* __restrict__ xr1 = x + (size_t)row1 * NN;

    // --- issue all global loads up front (fly under the setup scan) ---
    float4 wa0 = *(const float4*)(xr0 + 8 * tid);
    float4 wb0 = *(const float4*)(xr0 + 8 * tid + 4);
    float4 wa1 = *(const float4*)(xr1 + 8 * tid);
    float4 wb1 = *(const float4*)(xr1 + 8 * tid + 4);
    const float x00 = xr0[0];                  // uniform -> s_load
    const float x01 = xr1[0];

    // wave-edge threads (lane 0 of waves 1..3): neighbors' last element + its (c,s)
    float xm10 = 0.0f, xm11 = 0.0f, cm1 = 0.0f, sm1 = 0.0f;
    if (lane == 0 && wv > 0) {
        xm10 = xr0[8 * tid - 1];
        xm11 = xr1[8 * tid - 1];
        float2 t = cs[8 * tid - 1];
        cm1 = t.x; sm1 = t.y;
    }

    // --- per-thread (c,s) for its 8 steps (ws table, L1/L2-hot) ---
    float qc[8], qs[8];
    {
        const float4* cs4 = (const float4*)cs + tid * 4;
        #pragma unroll
        for (int h = 0; h < 4; ++h) {
            float4 v = cs4[h];
            qc[2*h] = v.x; qs[2*h] = v.y; qc[2*h+1] = v.z; qs[2*h+1] = v.w;
        }
    }

    // --- row-invariant scan state (hoisted) ---
    float Mt = ((qs[0]*qs[1])*(qs[2]*qs[3])) * ((qs[4]*qs[5])*(qs[6]*qs[7]));
    float Ms[6];
    float Mc = Mt;
    #pragma unroll
    for (int d = 1, st = 0; d < 64; d <<= 1, ++st) {
        Ms[st] = (lane + d < 64) ? Mc : 0.0f;   // predicate folded into multiplier
        float Mo = __shfl_down(Mc, d);
        if (lane + d < 64) Mc *= Mo;
    }
    const float Minc = Mc;                      // inclusive within-wave M suffix
    float MexW = __shfl_down(Mc, 1);
    if (lane == 63) MexW = 1.0f;                // exclusive version
    if (lane == 0) tmL[wv] = Minc;              // wave total M (inclusive at lane 0)
    __syncthreads();
    const float Tm1 = tmL[1], Tm2 = tmL[2], Tm3 = tmL[3];
    // cross-wave suffix coefficients: XU = k1*Tu1 + k2*Tu2 + k3*Tu3
    const float k1 = (wv == 0) ? 1.0f : 0.0f;
    const float k2 = (wv == 0) ? Tm1  : (wv == 1 ? 1.0f : 0.0f);
    const float k3 = (wv == 0) ? Tm1 * Tm2 : (wv == 1 ? Tm2 : (wv == 2 ? 1.0f : 0.0f));
    const float TmAbove = (wv == 0) ? Tm1 * Tm2 * Tm3
                        : (wv == 1) ? Tm2 * Tm3
                        : (wv == 2) ? Tm3 : 1.0f;

    // --- ring boundary: thread 0 patches t0 into wa.x of both rows ---
    if (tid == 0) {
        float2 csl = cs[NN - 1];
        wa0.x = csl.y * xr0[NN - 1] + csl.x * x00;
        wa1.x = csl.y * xr1[NN - 1] + csl.x * x01;
    }

    // --- pass 1: thread-local U, both rows interleaved (1 dep FMA/step) ---
    float U0, U1;
    U0 =      qc[7] * wb0.w;                     U1 =      qc[7] * wb1.w;
    U0 = fmaf(-qs[6], U0, qc[6] * wb0.z);        U1 = fmaf(-qs[6], U1, qc[6] * wb1.z);
    U0 = fmaf(-qs[5], U0, qc[5] * wb0.y);        U1 = fmaf(-qs[5], U1, qc[5] * wb1.y);
    U0 = fmaf(-qs[4], U0, qc[4] * wb0.x);        U1 = fmaf(-qs[4], U1, qc[4] * wb1.x);
    U0 = fmaf(-qs[3], U0, qc[3] * wa0.w);        U1 = fmaf(-qs[3], U1, qc[3] * wa1.w);
    U0 = fmaf(-qs[2], U0, qc[2] * wa0.z);        U1 = fmaf(-qs[2], U1, qc[2] * wa1.z);
    U0 = fmaf(-qs[1], U0, qc[1] * wa0.y);        U1 = fmaf(-qs[1], U1, qc[1] * wa1.y);
    U0 = fmaf(-qs[0], U0, qc[0] * wa0.x);        U1 = fmaf(-qs[0], U1, qc[0] * wa1.x);

    // --- wave suffix scan, both rows interleaved ---
    #pragma unroll
    for (int d = 1, st = 0; d < 64; d <<= 1, ++st) {
        float Uo0 = __shfl_down(U0, d);
        float Uo1 = __shfl_down(U1, d);
        U0 = fmaf(Ms[st], Uo0, U0);
        U1 = fmaf(Ms[st], Uo1, U1);
    }
    float Ux0 = __shfl_down(U0, 1);
    float Ux1 = __shfl_down(U1, 1);
    if (lane == 63) { Ux0 = 0.0f; Ux1 = 0.0f; }
    if (lane == 0) { tuL[0][wv] = U0; tuL[1][wv] = U1; }   // inclusive wave totals
    __syncthreads();
    float XU0 = k1 * tuL[0][1];  XU0 = fmaf(k2, tuL[0][2], XU0);  XU0 = fmaf(k3, tuL[0][3], XU0);
    float XU1 = k1 * tuL[1][1];  XU1 = fmaf(k2, tuL[1][2], XU1);  XU1 = fmaf(k3, tuL[1][3], XU1);
    const float h0 = fmaf(TmAbove, x00, XU0);
    const float h1 = fmaf(TmAbove, x01, XU1);
    float a0 = fmaf(MexW, h0, Ux0);              // own incoming carry
    float a1 = fmaf(MexW, h1, Ux1);
    const float aP0 = fmaf(Minc, h0, U0);        // = incoming carry of thread t-1
    const float aP1 = fmaf(Minc, h1, U1);

    // --- pass 2: emit, both rows interleaved; e_j -> y[8t+j+1] ---
    float e70 = fmaf(qc[7], a0, qs[7]*wb0.w);  a0 = fmaf(-qs[7], a0, qc[7]*wb0.w);
    float e71 = fmaf(qc[7], a1, qs[7]*wb1.w);  a1 = fmaf(-qs[7], a1, qc[7]*wb1.w);
    float e60 = fmaf(qc[6], a0, qs[6]*wb0.z);  a0 = fmaf(-qs[6], a0, qc[6]*wb0.z);
    float e61 = fmaf(qc[6], a1, qs[6]*wb1.z);  a1 = fmaf(-qs[6], a1, qc[6]*wb1.z);
    float e50 = fmaf(qc[5], a0, qs[5]*wb0.y);  a0 = fmaf(-qs[5], a0, qc[5]*wb0.y);
    float e51 = fmaf(qc[5], a1, qs[5]*wb1.y);  a1 = fmaf(-qs[5], a1, qc[5]*wb1.y);
    float e40 = fmaf(qc[4], a0, qs[4]*wb0.x);  a0 = fmaf(-qs[4], a0, qc[4]*wb0.x);
    float e41 = fmaf(qc[4], a1, qs[4]*wb1.x);  a1 = fmaf(-qs[4], a1, qc[4]*wb1.x);
    float e30 = fmaf(qc[3], a0, qs[3]*wa0.w);  a0 = fmaf(-qs[3], a0, qc[3]*wa0.w);
    float e31 = fmaf(qc[3], a1, qs[3]*wa1.w);  a1 = fmaf(-qs[3], a1, qc[3]*wa1.w);
    float e20 = fmaf(qc[2], a0, qs[2]*wa0.z);  a0 = fmaf(-qs[2], a0, qc[2]*wa0.z);
    float e21 = fmaf(qc[2], a1, qs[2]*wa1.z);  a1 = fmaf(-qs[2], a1, qc[2]*wa1.z);
    float e10 = fmaf(qc[1], a0, qs[1]*wa0.y);  a0 = fmaf(-qs[1], a0, qc[1]*wa0.y);
    float e11 = fmaf(qc[1], a1, qs[1]*wa1.y);  a1 = fmaf(-qs[1], a1, qc[1]*wa1.y);
    float e00 = fmaf(qc[0], a0, qs[0]*wa0.x);  a0 = fmaf(-qs[0], a0, qc[0]*wa0.x);
    float e01 = fmaf(qc[0], a1, qs[0]*wa1.x);  a1 = fmaf(-qs[0], a1, qc[0]*wa1.x);

    // --- slot 0 of each thread: prev thread's e7 ---
    float s00 = __shfl_up(e70, 1);               // within-wave neighbor
    float s01 = __shfl_up(e71, 1);
    if (lane == 0) {
        if (wv == 0) { s00 = a0; s01 = a1; }     // thread 0: y[0] = final carry
        else {                                   // wave edge: compute e7(t-1) locally
            s00 = fmaf(cm1, aP0, sm1 * xm10);
            s01 = fmaf(cm1, aP1, sm1 * xm11);
        }
    }

    // --- stores: two aligned float4 per thread, full-line coverage ---
    float* yr0 = y + (size_t)row0 * NN + 8 * tid;
    *(float4*)(yr0)     = make_float4(s00, e00, e10, e20);
    *(float4*)(yr0 + 4) = make_float4(e30, e40, e50, e60);
    if (st1) {
        float* yr1 = y + (size_t)row1 * NN + 8 * tid;
        *(float4*)(yr1)     = make_float4(s01, e01, e11, e21);
        *(float4*)(yr1 + 4) = make_float4(e31, e41, e51, e61);
    }
}

extern "C" void kernel_launch(void* const* d_in, const int* in_sizes, int n_in,
                              void* d_out, int out_size, void* d_ws, size_t ws_size,
                              hipStream_t stream) {
    const float* x      = (const float*)d_in[0];
    const float* angles = (const float*)d_in[1];
    float* y            = (float*)d_out;
    float2* cs          = (float2*)d_ws;           // 2048 * 8 B = 16 KB

    const int B = in_sizes[0] / NN;                // rows (16384)

    hipLaunchKernelGGL(cs_init_kernel, dim3(8), dim3(256), 0, stream, angles, cs);

    const int blocks = (B + 1) / 2;                // 8192 blocks x 256 thr, 2 rows each
    hipLaunchKernelGGL(ring_rows2_kernel, dim3(blocks), dim3(256), 0, stream,
                       x, (const float2*)cs, y, B);
}